// Round 3
// baseline (479.261 us; speedup 1.0000x reference)
//
#include <hip/hip_runtime.h>

// LSTM: B=2048 independent sequences, T=2048 serial steps, H=16, IN=1.
// One wave per batch element (2048 waves = 2/SIMD, the max TLP the problem
// allows), lane l = gate row l (i:0-15, f:16-31, g:32-47, o:48-63).
// Latency-bound => chain-shortening design:
//  - matvec: two independent 8-deep v_fmac_f32_dpp chains (pre-rotated,
//    pre-scaled W_hh) + 1 add.
//  - gate gather (i,f,g,o per unit): VALU-only via v_permlane16/32_swap
//    (runtime-probed semantics, per-lane mask select) instead of ds_bpermute
//    (~120cyc LDS latency on the chain). Fallback: bpermute path.
//  - constant folds: w/wih/bias pre-scaled by mco; c scaled by -2log2e.

__device__ __forceinline__ float i2f(int i) { return __int_as_float(i); }
__device__ __forceinline__ int   f2i(float f) { return __float_as_int(f); }

#define LOG2E 1.44269504088896340736f

#if __has_builtin(__builtin_amdgcn_permlane16_swap) && __has_builtin(__builtin_amdgcn_permlane32_swap)
#define HAVE_PERMSWAP 1
#else
#define HAVE_PERMSWAP 0
#endif

typedef unsigned __attribute__((ext_vector_type(2))) uint2v;

// Fused rotate+FMA: acc += h[(j +- n) & 15] * w   (one VALU instruction)
#define FMAC_DPP(acc, h_, w_, n)                                               \
    asm("v_fmac_f32_dpp %0, %1, %2 row_ror:" #n " row_mask:0xf bank_mask:0xf"  \
        : "+v"(acc) : "v"(h_), "v"(w_));
#define MUL_DPP(dst, h_, w_, n)                                                \
    asm("v_mul_f32_dpp %0, %1, %2 row_ror:" #n " row_mask:0xf bank_mask:0xf"   \
        : "=v"(dst) : "v"(h_), "v"(w_));

template<bool FAST>
__device__ __forceinline__ float lstm_run(
    const float* __restrict__ xp, const float (&w)[16],
    float wih_s, float bias_s, float aco, float bco,
    bool m16, bool m32, bool b4, bool b5,
    int a_i, int a_f, int a_g, int a_o, int l)
{
    float hcur = 0.0f, c = 0.0f;     // c holds -2log2e * c_real
    float xblk = xp[l];              // 64 timesteps staged per VGPR

#pragma unroll 1
    for (int blk = 0; blk < 32; ++blk) {
        const int nxt = (blk < 31) ? (blk + 1) : 31;
        float xnext = xp[nxt * 64 + l];          // prefetch next x block
#pragma unroll 1
        for (int sub = 0; sub < 4; ++sub) {
            const int base = sub << 4;           // runtime -> readlane SGPR idx
#pragma unroll
            for (int k = 0; k < 16; ++k) {
                float xs = i2f(__builtin_amdgcn_readlane(f2i(xblk), base + k));
                // --- matvec: two independent 8-deep chains ---
                float aA = fmaf(wih_s, xs, bias_s);
                aA = fmaf(hcur, w[0], aA);
                FMAC_DPP(aA, hcur, w[1], 1)
                FMAC_DPP(aA, hcur, w[2], 2)
                FMAC_DPP(aA, hcur, w[3], 3)
                FMAC_DPP(aA, hcur, w[4], 4)
                FMAC_DPP(aA, hcur, w[5], 5)
                FMAC_DPP(aA, hcur, w[6], 6)
                FMAC_DPP(aA, hcur, w[7], 7)
                float aB;
                MUL_DPP(aB, hcur, w[8], 8)
                FMAC_DPP(aB, hcur, w[9],  9)
                FMAC_DPP(aB, hcur, w[10], 10)
                FMAC_DPP(aB, hcur, w[11], 11)
                FMAC_DPP(aB, hcur, w[12], 12)
                FMAC_DPP(aB, hcur, w[13], 13)
                FMAC_DPP(aB, hcur, w[14], 14)
                FMAC_DPP(aB, hcur, w[15], 15)
                float acc = aA + aB;
                // --- activation (pre-scaled input) ---
                float e   = __builtin_amdgcn_exp2f(acc);
                float r   = __builtin_amdgcn_rcpf(1.0f + e);
                float act = fmaf(aco, r, bco);

                float f_, o_, ig;
                if constexpr (FAST) {
#if HAVE_PERMSWAP
                    // VALU gather: P1=act[l^16], P2=act[l^32], P3=act[l^48]
                    uint2v t16 = __builtin_amdgcn_permlane16_swap(
                        (unsigned)f2i(act), (unsigned)f2i(act), false, false);
                    float P1 = i2f(m16 ? (int)t16[0] : (int)t16[1]);
                    uint2v t32 = __builtin_amdgcn_permlane32_swap(
                        (unsigned)f2i(act), (unsigned)f2i(act), false, false);
                    float P2 = i2f(m32 ? (int)t32[0] : (int)t32[1]);
                    uint2v t48 = __builtin_amdgcn_permlane32_swap(
                        (unsigned)f2i(P1), (unsigned)f2i(P1), false, false);
                    float P3 = i2f(m32 ? (int)t48[0] : (int)t48[1]);
                    // row r holds: act=gate r, P1=gate r^1, P2=gate r^2, P3=gate r^3
                    float u  = b4 ? P1 : act;     // i or g
                    float v  = b4 ? P3 : P2;      // g or i
                    ig       = u * v;             // i*g, all rows
                    float fa = b5 ? P3 : P1;
                    float fb = b5 ? P2 : act;
                    f_       = b4 ? fb : fa;      // gate 1
                    float oa = b5 ? P1 : P3;
                    float ob = b5 ? act : P2;
                    o_       = b4 ? ob : oa;      // gate 3
#else
                    f_ = o_ = ig = 0.0f;          // never reached
#endif
                } else {
                    int ai = f2i(act);
                    float gi = i2f(__builtin_amdgcn_ds_bpermute(a_i, ai));
                    float gf = i2f(__builtin_amdgcn_ds_bpermute(a_f, ai));
                    float gg = i2f(__builtin_amdgcn_ds_bpermute(a_g, ai));
                    float go = i2f(__builtin_amdgcn_ds_bpermute(a_o, ai));
                    f_ = gf; o_ = go; ig = gi * gg;
                }

                c = fmaf(f_, c, ig);              // scaled c recurrence
                float e2 = __builtin_amdgcn_exp2f(c);
                float r2 = __builtin_amdgcn_rcpf(1.0f + e2);
                float th = fmaf(2.0f, r2, -1.0f);
                hcur = o_ * th;
            }
        }
        xblk = xnext;
    }
    return hcur;
}

__global__ __launch_bounds__(256) void lstm_fused(
    const float* __restrict__ x,
    const float* __restrict__ Wih,
    const float* __restrict__ Whh,
    const float* __restrict__ bih,
    const float* __restrict__ bhh,
    const float* __restrict__ Wfc,
    const float* __restrict__ bfc,
    float* __restrict__ out)
{
    const int T   = 2048;
    const int tid = blockIdx.x * blockDim.x + threadIdx.x;
    const int b   = tid >> 6;            // one wave per batch element
    const int l   = threadIdx.x & 63;    // gate row
    const int j   = l & 15;              // hidden unit
    const int gate = l >> 4;             // 0:i 1:f 2:g 3:o
    const bool b4 = (l >> 4) & 1;
    const bool b5 = (l >> 5) & 1;

    // Probe DPP row_ror direction (for w pre-rotation).
    int probe = __builtin_amdgcn_mov_dpp(j, 0x121, 0xF, 0xF, true);
    const int dir = (probe == ((j + 1) & 15)) ? 1 : -1;

    // sigmoid(z)=rcp(1+exp2(-log2e*z)); tanh(z)=2*rcp(1+exp2(-2log2e*z))-1
    const float mco = (gate == 2) ? (-2.0f * LOG2E) : (-LOG2E);
    // g-gate affine also folds the -2log2e scale of c:
    const float aco = (gate == 2) ? (-4.0f * LOG2E) : 1.0f;
    const float bco = (gate == 2) ? ( 2.0f * LOG2E) : 0.0f;

    float w[16];
#pragma unroll
    for (int s = 0; s < 16; ++s) {
        int kk = (j + s * dir + 32) & 15;
        w[s] = Whh[l * 16 + kk] * mco;
    }
    const float wih_s  = Wih[l] * mco;
    const float bias_s = (bih[l] + bhh[l]) * mco;

    // bpermute byte addresses (slow-path gather)
    const int a_i = (j     ) << 2;
    const int a_f = (j + 16) << 2;
    const int a_g = (j + 32) << 2;
    const int a_o = (j + 48) << 2;

    // Runtime probe of permlane swap semantics (lane-id test, data-independent).
    bool fast = false, m16 = false, m32 = false;
#if HAVE_PERMSWAP
    {
        uint2v p = __builtin_amdgcn_permlane16_swap((unsigned)l, (unsigned)l,
                                                    false, false);
        int want16 = l ^ 16;
        m16 = ((int)p[0] == want16);
        int got16 = m16 ? (int)p[0] : (int)p[1];
        uint2v q = __builtin_amdgcn_permlane32_swap((unsigned)l, (unsigned)l,
                                                    false, false);
        int want32 = l ^ 32;
        m32 = ((int)q[0] == want32);
        int got32 = m32 ? (int)q[0] : (int)q[1];
        fast = __all(got16 == want16) && __all(got32 == want32);
    }
#endif

    const float* xp = x + (size_t)b * T;
    float hcur;
    if (fast)
        hcur = lstm_run<true >(xp, w, wih_s, bias_s, aco, bco, m16, m32, b4, b5,
                               a_i, a_f, a_g, a_o, l);
    else
        hcur = lstm_run<false>(xp, w, wih_s, bias_s, aco, bco, m16, m32, b4, b5,
                               a_i, a_f, a_g, a_o, l);

    // out[b] = sum_j Wfc[j]*h[j] + bfc ; h replicated 4x -> scale by 0.25
    float p = hcur * (Wfc[j] * 0.25f);
    p += __shfl_xor(p, 32);
    p += __shfl_xor(p, 16);
    p += __shfl_xor(p, 8);
    p += __shfl_xor(p, 4);
    p += __shfl_xor(p, 2);
    p += __shfl_xor(p, 1);
    if (l == 0) out[b] = p + bfc[0];
}

extern "C" void kernel_launch(void* const* d_in, const int* in_sizes, int n_in,
                              void* d_out, int out_size, void* d_ws, size_t ws_size,
                              hipStream_t stream) {
    const float* x   = (const float*)d_in[0];
    const float* Wih = (const float*)d_in[1];
    const float* Whh = (const float*)d_in[2];
    const float* bih = (const float*)d_in[3];
    const float* bhh = (const float*)d_in[4];
    const float* Wfc = (const float*)d_in[5];
    const float* bfc = (const float*)d_in[6];
    float* out = (float*)d_out;

    const int B = 2048;
    const int threads = 256;               // 4 waves/block, 1 batch elem per wave
    const int blocks = (B * 64) / threads; // 512 blocks -> 2 waves/SIMD
    hipLaunchKernelGGL(lstm_fused, dim3(blocks), dim3(threads), 0, stream,
                       x, Wih, Whh, bih, bhh, Wfc, bfc, out);
}

// Round 5
// 403.720 us; speedup vs baseline: 1.1871x; 1.1871x over previous
//
#include <hip/hip_runtime.h>

// LSTM: B=2048 independent sequences, T=2048 serial steps, H=16, IN=1.
// One wave per batch element (2048 waves = 2/SIMD max TLP), lane l = gate
// row l (i:0-15, f:16-31, g:32-47, o:48-63).
// R5 = R2's proven kernel (375us, absmax 0.0) + ONE change under test:
// __launch_bounds__(256,2) + waves_per_eu(2,2) so the allocator uses the
// 256-VGPR/wave budget our 2-wave/EU launch allows, instead of parking
// w[16]/temps in AGPRs (hidden v_accvgpr_* VALU traffic, suspected from
// VGPR_Count=28-32 + dynamic VALU ~1.7-2x static count in R1-R3).
// Matvec: fused v_fmac_f32_dpp row_ror against pre-rotated, pre-scaled W_hh.
// Gather: 4x ds_bpermute. Folds: w/wih/bias pre-scaled by mco; c scaled by
// -2log2e. (R4's x pre-transform bug reverted: readlane RAW x, then per-lane
// fmaf with this lane's own wih_s/bias_s.)

__device__ __forceinline__ float i2f(int i) { return __int_as_float(i); }
__device__ __forceinline__ int   f2i(float f) { return __float_as_int(f); }

#define LOG2E 1.44269504088896340736f

// Fused rotate+FMA: acc += h[(j +- n) & 15] * w   (one VALU instruction)
#define FMAC_DPP(acc, h_, w_, n)                                               \
    asm("v_fmac_f32_dpp %0, %1, %2 row_ror:" #n " row_mask:0xf bank_mask:0xf"  \
        : "+v"(acc) : "v"(h_), "v"(w_));
#define MUL_DPP(dst, h_, w_, n)                                                \
    asm("v_mul_f32_dpp %0, %1, %2 row_ror:" #n " row_mask:0xf bank_mask:0xf"   \
        : "=v"(dst) : "v"(h_), "v"(w_));

#define STEP(s_imm) {                                                        \
    float xs_ = i2f(__builtin_amdgcn_readlane(f2i(xblk), (s_imm)));          \
    float aA_ = fmaf(wih_s, xs_, bias_s);                                    \
    aA_ = fmaf(hcur, w[0], aA_);                                             \
    FMAC_DPP(aA_, hcur, w[1], 1)                                             \
    FMAC_DPP(aA_, hcur, w[2], 2)                                             \
    FMAC_DPP(aA_, hcur, w[3], 3)                                             \
    FMAC_DPP(aA_, hcur, w[4], 4)                                             \
    FMAC_DPP(aA_, hcur, w[5], 5)                                             \
    FMAC_DPP(aA_, hcur, w[6], 6)                                             \
    FMAC_DPP(aA_, hcur, w[7], 7)                                             \
    float aB_;                                                               \
    MUL_DPP(aB_, hcur, w[8], 8)                                              \
    FMAC_DPP(aB_, hcur, w[9],  9)                                            \
    FMAC_DPP(aB_, hcur, w[10], 10)                                           \
    FMAC_DPP(aB_, hcur, w[11], 11)                                           \
    FMAC_DPP(aB_, hcur, w[12], 12)                                           \
    FMAC_DPP(aB_, hcur, w[13], 13)                                           \
    FMAC_DPP(aB_, hcur, w[14], 14)                                           \
    FMAC_DPP(aB_, hcur, w[15], 15)                                           \
    float acc_ = aA_ + aB_;                                                  \
    float e_   = __builtin_amdgcn_exp2f(acc_);          /* pre-scaled */     \
    float r_   = __builtin_amdgcn_rcpf(1.0f + e_);                           \
    float act_ = fmaf(aco, r_, bco);                                         \
    int   ai_  = f2i(act_);                                                  \
    float gi_  = i2f(__builtin_amdgcn_ds_bpermute(addr_i, ai_));             \
    float gf_  = i2f(__builtin_amdgcn_ds_bpermute(addr_f, ai_));             \
    float gg_  = i2f(__builtin_amdgcn_ds_bpermute(addr_g, ai_));             \
    float go_  = i2f(__builtin_amdgcn_ds_bpermute(addr_o, ai_));             \
    c = fmaf(gf_, c, gi_ * gg_);          /* c is scaled by -2*log2e */      \
    float e2_ = __builtin_amdgcn_exp2f(c);                                   \
    float r2_ = __builtin_amdgcn_rcpf(1.0f + e2_);                           \
    float th_ = fmaf(2.0f, r2_, -1.0f);                                      \
    hcur = go_ * th_;                                                        \
}

#define STEP8(base) STEP(base+0) STEP(base+1) STEP(base+2) STEP(base+3) \
                    STEP(base+4) STEP(base+5) STEP(base+6) STEP(base+7)

__global__ __launch_bounds__(256, 2)
__attribute__((amdgpu_waves_per_eu(2, 2)))
void lstm_fused(
    const float* __restrict__ x,
    const float* __restrict__ Wih,
    const float* __restrict__ Whh,
    const float* __restrict__ bih,
    const float* __restrict__ bhh,
    const float* __restrict__ Wfc,
    const float* __restrict__ bfc,
    float* __restrict__ out)
{
    const int T   = 2048;
    const int tid = blockIdx.x * blockDim.x + threadIdx.x;
    const int b   = tid >> 6;            // one wave per batch element
    const int l   = threadIdx.x & 63;    // gate row
    const int j   = l & 15;              // hidden unit
    const int gate = l >> 4;             // 0:i 1:f 2:g 3:o

    // Probe DPP row_ror direction: after ror:1, lane l holds j from lane (l+-1)&15.
    int probe = __builtin_amdgcn_mov_dpp(j, 0x121, 0xF, 0xF, true);
    const int dir = (probe == ((j + 1) & 15)) ? 1 : -1;

    // sigmoid(z)=rcp(1+exp2(-log2e*z)); tanh(z)=2*rcp(1+exp2(-2log2e*z))-1
    const float mco = (gate == 2) ? (-2.0f * LOG2E) : (-LOG2E);
    // g-gate affine also folds the -2log2e scale of c:
    const float aco = (gate == 2) ? (-4.0f * LOG2E) : 1.0f;
    const float bco = (gate == 2) ? ( 2.0f * LOG2E) : 0.0f;

    // Pre-rotated + pre-scaled W_hh row: w[s] pairs with row_ror:s of h.
    float w[16];
#pragma unroll
    for (int s = 0; s < 16; ++s) {
        int k = (j + s * dir + 32) & 15;
        w[s] = Whh[l * 16 + k] * mco;
    }

    const float wih_s  = Wih[l] * mco;            // IN = 1
    const float bias_s = (bih[l] + bhh[l]) * mco;

    // bpermute byte addresses for gathering i,f,g,o of unit j
    const int addr_i = (j     ) << 2;
    const int addr_f = (j + 16) << 2;
    const int addr_g = (j + 32) << 2;
    const int addr_o = (j + 48) << 2;

    const float* xp = x + (size_t)b * T;
    float xblk = xp[l];                  // x staged 64 timesteps per VGPR

    float hcur = 0.0f, c = 0.0f;         // c holds -2log2e * c_real

#pragma unroll 1
    for (int blk = 0; blk < 32; ++blk) {
        const int nxt = (blk < 31) ? (blk + 1) : 31;
        float xnext = xp[nxt * 64 + l];  // prefetch next x block (vmcnt path)
        STEP8(0) STEP8(8) STEP8(16) STEP8(24)
        STEP8(32) STEP8(40) STEP8(48) STEP8(56)
        xblk = xnext;
    }

    // out[b] = sum_j Wfc[j]*h[j] + bfc ; h replicated 4x -> scale by 0.25
    float p = hcur * (Wfc[j] * 0.25f);
    p += __shfl_xor(p, 32);
    p += __shfl_xor(p, 16);
    p += __shfl_xor(p, 8);
    p += __shfl_xor(p, 4);
    p += __shfl_xor(p, 2);
    p += __shfl_xor(p, 1);
    if (l == 0) out[b] = p + bfc[0];
}

extern "C" void kernel_launch(void* const* d_in, const int* in_sizes, int n_in,
                              void* d_out, int out_size, void* d_ws, size_t ws_size,
                              hipStream_t stream) {
    const float* x   = (const float*)d_in[0];
    const float* Wih = (const float*)d_in[1];
    const float* Whh = (const float*)d_in[2];
    const float* bih = (const float*)d_in[3];
    const float* bhh = (const float*)d_in[4];
    const float* Wfc = (const float*)d_in[5];
    const float* bfc = (const float*)d_in[6];
    float* out = (float*)d_out;

    const int B = 2048;
    const int threads = 256;               // 4 waves/block, 1 batch elem per wave
    const int blocks = (B * 64) / threads; // 512 blocks -> 2 waves/SIMD
    hipLaunchKernelGGL(lstm_fused, dim3(blocks), dim3(threads), 0, stream,
                       x, Wih, Whh, bih, bhh, Wfc, bfc, out);
}